// Round 6
// baseline (207.349 us; speedup 1.0000x reference)
//
#include <hip/hip_runtime.h>
#include <cmath>

#define T_LEN   480000
#define BATCH   64
#define CHUNK   16                       /* samples per thread */
#define WARM    16                       /* |pole|=0.414 -> 0.414^16 ~ 7.6e-7 */
#define TPB     256
#define TS      (TPB * CHUNK)            /* 4096 samples per tile */
#define TPR     ((T_LEN + TS - 1) / TS)  /* 118 tiles per row */
#define TPB_TILES 4                      /* tiles per block, pipelined */
#define BPR     ((TPR + TPB_TILES - 1) / TPB_TILES)   /* 30 blocks per row */
#define NLOAD_MAX (TS + WARM)            /* 4112 */
#define NITER   ((NLOAD_MAX + TPB * 4 - 1) / (TPB * 4))   /* 5 */
/* quad skew: +4 floats per 32 -> aligned float4 stays contiguous, all
   access patterns bank-uniform (8 lanes/quad). */
#define LDS_SLOTS (NLOAD_MAX + ((NLOAD_MAX >> 5) << 2))  /* 18.5 KB */

/* native vector type: __builtin_nontemporal_* rejects HIP_vector_type */
typedef float f32x4 __attribute__((ext_vector_type(4)));

__device__ __forceinline__ int slot4(int i) { return i + ((i >> 5) << 2); }

#define STEP(XN, YN)                                            \
    {                                                           \
        float u_ = fmaf(B0, (XN), fmaf(B1, x1, B2 * x2));       \
        (YN) = fmaf(-A1, y1, fmaf(-A2, y2, u_));                \
        x2 = x1; x1 = (XN); y2 = y1; y1 = (YN);                 \
    }

/* R6: R5 (nt loads + LDS-staged nt stores; fixed the L2/LLC churn, ~77->~60us)
   + R2's persistent pipelined tiles.  With the churn wall gone, the remaining
   cost model is phase serialization: loads only in flight during phase 1.
   Prefetching tile k+1 during tile k's compute+store keeps the read stream
   continuously in flight; vmcnt drain happens at the NEXT commit, fully
   overlapped. */

__global__ __launch_bounds__(TPB) void allpass_kernel(
    const float* __restrict__ x, float* __restrict__ y,
    float B0, float B1, float B2, float A1, float A2)
{
    __shared__ __align__(16) float lds[LDS_SLOTS];
    const int tid  = threadIdx.x;
    const int row  = blockIdx.x / BPR;
    const int tb0  = (blockIdx.x % BPR) * TPB_TILES;
    const int ntile = min(TPB_TILES, TPR - tb0);
    const float* __restrict__ xrow = x + (size_t)row * T_LEN;
    float* __restrict__ yrow       = y + (size_t)row * T_LEN;

    /* ---- prologue: prefetch tile tb0 (nt, back-to-back) ---- */
    int sbase = tb0 * TS;
    int ns    = min(TS, T_LEN - sbase);
    int nload = ns + WARM;
    f32x4 vbuf[NITER];
    #pragma unroll
    for (int j = 0; j < NITER; ++j) {
        const int i4 = tid * 4 + j * (TPB * 4);
        if (i4 < nload) {
            if (tb0 == 0 && i4 < WARM)
                vbuf[j] = (f32x4){0.f, 0.f, 0.f, 0.f};  /* state before t=0 */
            else
                vbuf[j] = __builtin_nontemporal_load(
                              (const f32x4*)(xrow + sbase - WARM + i4));
        }
    }

    for (int it = 0; it < ntile; ++it) {
        /* ---- commit prefetched x -> LDS (implicit vmcnt wait here) ---- */
        #pragma unroll
        for (int j = 0; j < NITER; ++j) {
            const int i4 = tid * 4 + j * (TPB * 4);
            if (i4 < nload)
                *(f32x4*)&lds[slot4(i4)] = vbuf[j];
        }
        __syncthreads();

        const int cur_sbase = sbase, cur_ns = ns;

        /* ---- issue NEXT tile's nt loads; wait deferred to next commit ---- */
        if (it + 1 < ntile) {
            const int tb = tb0 + it + 1;
            sbase = tb * TS;
            ns    = min(TS, T_LEN - sbase);
            nload = ns + WARM;
            #pragma unroll
            for (int j = 0; j < NITER; ++j) {
                const int i4 = tid * 4 + j * (TPB * 4);
                if (i4 < nload)             /* tb>=1: no zero-fill path */
                    vbuf[j] = __builtin_nontemporal_load(
                                  (const f32x4*)(xrow + sbase - WARM + i4));
            }
        }

        /* ---- compute: 16 warm-up + 16 real steps from LDS ---- */
        f32x4 yq[CHUNK / 4];
        const int ls = tid * CHUNK;
        const bool active = (ls < cur_ns);
        if (active) {
            float x1 = 0.f, x2 = 0.f, y1 = 0.f, y2 = 0.f;
            #pragma unroll
            for (int t4 = 0; t4 < WARM; t4 += 4) {
                f32x4 xv = *(const f32x4*)&lds[slot4(ls + t4)];
                float t;
                STEP(xv.x, t); STEP(xv.y, t); STEP(xv.z, t); STEP(xv.w, t);
            }
            #pragma unroll
            for (int t4 = 0; t4 < CHUNK; t4 += 4) {
                f32x4 xv = *(const f32x4*)&lds[slot4(ls + WARM + t4)];
                f32x4 yv;
                STEP(xv.x, yv.x); STEP(xv.y, yv.y);
                STEP(xv.z, yv.z); STEP(xv.w, yv.w);
                yq[t4 / 4] = yv;
            }
        }
        __syncthreads();                      /* all LDS x-reads done */

        /* ---- stage y -> LDS, then lane-contiguous nt stores ---- */
        if (active) {
            #pragma unroll
            for (int t4 = 0; t4 < CHUNK; t4 += 4)
                *(f32x4*)&lds[slot4(ls + t4)] = yq[t4 / 4];
        }
        __syncthreads();

        #pragma unroll
        for (int j = 0; j < NITER - 1; ++j) { /* 4 iters cover TS */
            const int i4 = tid * 4 + j * (TPB * 4);
            if (i4 < cur_ns) {
                f32x4 v = *(const f32x4*)&lds[slot4(i4)];
                __builtin_nontemporal_store(v, (f32x4*)(yrow + cur_sbase + i4));
            }
        }
        __syncthreads();                      /* LDS store-reads done before next commit */
    }
}

extern "C" void kernel_launch(void* const* d_in, const int* in_sizes, int n_in,
                              void* d_out, int out_size, void* d_ws, size_t ws_size,
                              hipStream_t stream) {
    const float* x = (const float*)d_in[0];
    float* y = (float*)d_out;

    const double sample_rate = 16000.0, central_freq = 4000.0, Q = 0.707;
    const double w0 = 2.0 * M_PI * central_freq / sample_rate;
    const double alpha = sin(w0) / (2.0 * Q);
    const double cw = cos(w0);
    const double a0 = 1.0 + alpha;
    const float B0 = (float)((1.0 - alpha) / a0);
    const float B1 = (float)((-2.0 * cw) / a0);
    const float B2 = (float)((1.0 + alpha) / a0);
    const float A1 = (float)((-2.0 * cw) / a0);
    const float A2 = (float)((1.0 - alpha) / a0);

    const int blocks = BATCH * BPR;   /* 1920 */
    allpass_kernel<<<blocks, TPB, 0, stream>>>(x, y, B0, B1, B2, A1, A2);
}

// Round 7
// 206.957 us; speedup vs baseline: 1.0019x; 1.0019x over previous
//
#include <hip/hip_runtime.h>
#include <cmath>

#define T_LEN   480000
#define BATCH   64
#define CHUNK   16                       /* samples per thread */
#define WARM    16                       /* |pole|=0.414 -> 0.414^16 ~ 7.6e-7 */
#define TPB     256
#define TS      (TPB * CHUNK)            /* 4096 samples per tile */
#define TPR     ((T_LEN + TS - 1) / TS)  /* 118 tiles per row */
#define TPB_TILES 4                      /* tiles per block, pipelined */
#define BPR     ((TPR + TPB_TILES - 1) / TPB_TILES)   /* 30 blocks per row */
#define NLOAD_MAX (TS + WARM)            /* 4112 */
#define NITER   ((NLOAD_MAX + TPB * 4 - 1) / (TPB * 4))   /* 5 */
/* quad skew: +4 floats per 32 -> aligned float4 stays contiguous, all
   access patterns bank-uniform (8 lanes/quad). */
#define XSLOTS  (NLOAD_MAX + ((NLOAD_MAX >> 5) << 2))    /* 4624 fl = 18.5 KB */
#define YSLOTS  (TS + ((TS >> 5) << 2))                  /* 4608 fl = 18.4 KB */

/* native vector type: __builtin_nontemporal_* rejects HIP_vector_type */
typedef float f32x4 __attribute__((ext_vector_type(4)));

__device__ __forceinline__ int slot4(int i) { return i + ((i >> 5) << 2); }

#define STEP(XN, YN)                                            \
    {                                                           \
        float u_ = fmaf(B0, (XN), fmaf(B1, x1, B2 * x2));       \
        (YN) = fmaf(-A1, y1, fmaf(-A2, y2, u_));                \
        x2 = x1; x1 = (XN); y2 = y1; y1 = (YN);                 \
    }

/* R7: R6 (nt streams + persistent pipelined tiles) with the barrier count
   halved.  x and y now live in SEPARATE LDS regions, so:
     A: commit vbuf->xs            (prev x-reads ended at prev barrier2)
        barrier1
     B: issue next nt loads; compute from xs; stage y->ys (no region clash)
        barrier2
     C: read ys -> nt store        (vs next B's ys-writes: fenced by barrier1)
   2 barriers/tile instead of 4; C flows barrier-free into next A. */

__global__ __launch_bounds__(TPB) void allpass_kernel(
    const float* __restrict__ x, float* __restrict__ y,
    float B0, float B1, float B2, float A1, float A2)
{
    __shared__ __align__(16) float xs[XSLOTS];
    __shared__ __align__(16) float ys[YSLOTS];
    const int tid  = threadIdx.x;
    const int row  = blockIdx.x / BPR;
    const int tb0  = (blockIdx.x % BPR) * TPB_TILES;
    const int ntile = min(TPB_TILES, TPR - tb0);
    const float* __restrict__ xrow = x + (size_t)row * T_LEN;
    float* __restrict__ yrow       = y + (size_t)row * T_LEN;

    /* ---- prologue: prefetch tile tb0 (nt, back-to-back) ---- */
    int sbase = tb0 * TS;
    int ns    = min(TS, T_LEN - sbase);
    int nload = ns + WARM;
    f32x4 vbuf[NITER];
    #pragma unroll
    for (int j = 0; j < NITER; ++j) {
        const int i4 = tid * 4 + j * (TPB * 4);
        if (i4 < nload) {
            if (tb0 == 0 && i4 < WARM)
                vbuf[j] = (f32x4){0.f, 0.f, 0.f, 0.f};  /* state before t=0 */
            else
                vbuf[j] = __builtin_nontemporal_load(
                              (const f32x4*)(xrow + sbase - WARM + i4));
        }
    }

    for (int it = 0; it < ntile; ++it) {
        /* ---- A: commit prefetched x -> xs ---- */
        #pragma unroll
        for (int j = 0; j < NITER; ++j) {
            const int i4 = tid * 4 + j * (TPB * 4);
            if (i4 < nload)
                *(f32x4*)&xs[slot4(i4)] = vbuf[j];
        }
        __syncthreads();                      /* barrier1 */

        const int cur_sbase = sbase, cur_ns = ns;

        /* ---- B: issue NEXT tile's nt loads (overlap with compute) ---- */
        if (it + 1 < ntile) {
            const int tb = tb0 + it + 1;
            sbase = tb * TS;
            ns    = min(TS, T_LEN - sbase);
            nload = ns + WARM;
            #pragma unroll
            for (int j = 0; j < NITER; ++j) {
                const int i4 = tid * 4 + j * (TPB * 4);
                if (i4 < nload)             /* tb>=1: no zero-fill path */
                    vbuf[j] = __builtin_nontemporal_load(
                                  (const f32x4*)(xrow + sbase - WARM + i4));
            }
        }

        /* ---- B: compute 16 warm-up + 16 real steps, stage y -> ys ---- */
        const int ls = tid * CHUNK;
        if (ls < cur_ns) {
            float x1 = 0.f, x2 = 0.f, y1 = 0.f, y2 = 0.f;
            #pragma unroll
            for (int t4 = 0; t4 < WARM; t4 += 4) {
                f32x4 xv = *(const f32x4*)&xs[slot4(ls + t4)];
                float t;
                STEP(xv.x, t); STEP(xv.y, t); STEP(xv.z, t); STEP(xv.w, t);
            }
            #pragma unroll
            for (int t4 = 0; t4 < CHUNK; t4 += 4) {
                f32x4 xv = *(const f32x4*)&xs[slot4(ls + WARM + t4)];
                f32x4 yv;
                STEP(xv.x, yv.x); STEP(xv.y, yv.y);
                STEP(xv.z, yv.z); STEP(xv.w, yv.w);
                *(f32x4*)&ys[slot4(ls + t4)] = yv;
            }
        }
        __syncthreads();                      /* barrier2 */

        /* ---- C: lane-contiguous nt stores from ys (no trailing barrier:
           next tile's ys writes sit behind barrier1) ---- */
        #pragma unroll
        for (int j = 0; j < NITER - 1; ++j) { /* 4 iters cover TS */
            const int i4 = tid * 4 + j * (TPB * 4);
            if (i4 < cur_ns) {
                f32x4 v = *(const f32x4*)&ys[slot4(i4)];
                __builtin_nontemporal_store(v, (f32x4*)(yrow + cur_sbase + i4));
            }
        }
    }
}

extern "C" void kernel_launch(void* const* d_in, const int* in_sizes, int n_in,
                              void* d_out, int out_size, void* d_ws, size_t ws_size,
                              hipStream_t stream) {
    const float* x = (const float*)d_in[0];
    float* y = (float*)d_out;

    const double sample_rate = 16000.0, central_freq = 4000.0, Q = 0.707;
    const double w0 = 2.0 * M_PI * central_freq / sample_rate;
    const double alpha = sin(w0) / (2.0 * Q);
    const double cw = cos(w0);
    const double a0 = 1.0 + alpha;
    const float B0 = (float)((1.0 - alpha) / a0);
    const float B1 = (float)((-2.0 * cw) / a0);
    const float B2 = (float)((1.0 + alpha) / a0);
    const float A1 = (float)((-2.0 * cw) / a0);
    const float A2 = (float)((1.0 - alpha) / a0);

    const int blocks = BATCH * BPR;   /* 1920 */
    allpass_kernel<<<blocks, TPB, 0, stream>>>(x, y, B0, B1, B2, A1, A2);
}